// Round 9
// baseline (542.911 us; speedup 1.0000x reference)
//
#include <hip/hip_runtime.h>
#include <math.h>

typedef unsigned long long u64;
typedef _Float16 h2 __attribute__((ext_vector_type(2)));

#define N_PTS 12000
#define KNN 16
#define TJ 256     // candidate tile size
#define Q 4        // queries per wave
#define WPB 4      // waves per block
#define NTILES ((N_PTS + TJ - 1) / TJ)   // 47
#define TAU_TILES 4                      // sample = first 1024 points
#define CAP 448                          // survivor capacity; 7 offers/lane
#define HSTR (TJ + 2)                    // u32 row stride for f16 tile
#define MARGIN 0.08f                     // > 2*m, m = f16 d2 error bound 0.032

// ---------------------------------------------------------------------------
// Kernel 1: encoders. feats = tanh(x@Wf+bf); coords = tanh(x@Wl+bl) in fp32
// AND f16 (the f16 copy drives the sound approximate gate); sq = |coords|^2.
// ---------------------------------------------------------------------------
__global__ __launch_bounds__(256) void encoder_kernel(
    const float* __restrict__ x, const float* __restrict__ Wf, const float* __restrict__ bf,
    const float* __restrict__ Wl, const float* __restrict__ bl,
    float* __restrict__ feats, float* __restrict__ coords, _Float16* __restrict__ coords_h,
    float* __restrict__ sq)
{
  const int wave = threadIdx.x >> 6;
  const int lane = threadIdx.x & 63;
  const int i = blockIdx.x * 4 + wave;
  if (i >= N_PTS) return;
  float xv = x[i * 64 + lane];
  float accf = bf[lane];
  float accc = bl[lane & 15];
  #pragma unroll
  for (int k = 0; k < 64; ++k) {
    float xk = __shfl(xv, k);
    accf = fmaf(xk, Wf[k * 64 + lane], accf);
    accc = fmaf(xk, Wl[k * 16 + (lane & 15)], accc);
  }
  feats[i * 64 + lane] = tanhf(accf);
  float c = tanhf(accc);
  float cc = (lane < 16) ? c * c : 0.0f;
  cc += __shfl_xor(cc, 1);
  cc += __shfl_xor(cc, 2);
  cc += __shfl_xor(cc, 4);
  cc += __shfl_xor(cc, 8);
  if (lane < 16) {
    coords[i * 16 + lane] = c;
    coords_h[i * 16 + lane] = (_Float16)c;
  }
  if (lane == 0) sq[i] = cc;
}

// ---------------------------------------------------------------------------
// u64-key helpers. Keys (f32bits(d2)<<32)|j unique; sentinels (0x7F00000t<<32)
// exceed any real key; ~0ull matches no slot.
// ---------------------------------------------------------------------------
__device__ __forceinline__ void ins7(u64 key, u64* k7, u64& kmax) {
  const u64 om = (key < kmax) ? kmax : ~0ull;
  #pragma unroll
  for (int t = 0; t < 7; ++t)
    k7[t] = (k7[t] == om) ? key : k7[t];
  u64 a = k7[0] > k7[1] ? k7[0] : k7[1];
  u64 b = k7[2] > k7[3] ? k7[2] : k7[3];
  u64 c = k7[4] > k7[5] ? k7[4] : k7[5];
  a = a > b ? a : b;
  c = c > k7[6] ? c : k7[6];
  kmax = a > c ? a : c;
}

__device__ __forceinline__ void ins8(u64 key, u64* k8, u64& kmax) {
  const u64 om = (key < kmax) ? kmax : ~0ull;
  #pragma unroll
  for (int t = 0; t < 8; ++t)
    k8[t] = (k8[t] == om) ? key : k8[t];
  u64 a = k8[0] > k8[1] ? k8[0] : k8[1];
  u64 b = k8[2] > k8[3] ? k8[2] : k8[3];
  u64 c = k8[4] > k8[5] ? k8[4] : k8[5];
  u64 d = k8[6] > k8[7] ? k8[6] : k8[7];
  a = a > b ? a : b;
  c = c > d ? c : d;
  kmax = a > c ? a : c;
}

__device__ __forceinline__ u64 shflx_u64(u64 v, int off) {
  int lo = __shfl_xor((int)(unsigned)v, off);
  int hi = __shfl_xor((int)(unsigned)(v >> 32), off);
  return ((u64)(unsigned)hi << 32) | (unsigned)lo;
}

__device__ __forceinline__ u64 minbfly(u64 m) {
  #pragma unroll
  for (int off = 32; off >= 1; off >>= 1) {
    u64 o = shflx_u64(m, off);
    m = (o < m) ? o : m;
  }
  return m;
}

// ---------------------------------------------------------------------------
// Kernel 2: KNN + gaussian aggregation + fused output GEMM. Wave = 4 queries.
// Phase A (f16 dots): per-lane min over 1024-pt sample; tau = 16th order stat
//   of lane minima. Sound gate threshold = tau + MARGIN (covers 2x f16 error).
// Phase B (f16 dots): full scan, push survivor u16 indices (self/pad allowed,
//   filtered later). Overflow -> flag -> fixup.
// Phase C: exact fp32 re-score of survivors (reference-identical arithmetic),
//   exact top-16 via 7-slot tables (<=7 offers/lane: no eviction) + minbfly;
//   then out = concat(feats,agg)@Wo + bo via register shuffles.
// ---------------------------------------------------------------------------
__global__ __launch_bounds__(256) void knn_agg_kernel(
    const float* __restrict__ coords, const _Float16* __restrict__ coords_h,
    const float* __restrict__ sq, const float* __restrict__ feats,
    const float* __restrict__ Wo, const float* __restrict__ bo,
    float* __restrict__ out, int* __restrict__ flags)
{
  __shared__ unsigned cTh[8 * HSTR];              //  8256 B (f16 pairs, row w)
  __shared__ float sqs[TJ];                       //  1024 B
  __shared__ unsigned short sbuf[WPB * Q][CAP];   // 14336 B
  __shared__ int scnt[WPB * Q];                   //    64 B

  const int lane = threadIdx.x & 63;
  const int wave = threadIdx.x >> 6;
  const int qbase = blockIdx.x * (WPB * Q) + wave * Q;

  if (threadIdx.x < WPB * Q) scnt[threadIdx.x] = 0;

  // f16 query coords (bit-identical to staged candidate values) + exact sq
  unsigned ciq[Q][8];
  float sqi[Q];
  #pragma unroll
  for (int q = 0; q < Q; ++q) {
    const uint2* cp = (const uint2*)(coords_h + (qbase + q) * 16);
    uint2 a = cp[0], b = cp[1], c = cp[2], d = cp[3];
    ciq[q][0] = a.x; ciq[q][1] = a.y; ciq[q][2] = b.x; ciq[q][3] = b.y;
    ciq[q][4] = c.x; ciq[q][5] = c.y; ciq[q][6] = d.x; ciq[q][7] = d.y;
    sqi[q] = sq[qbase + q];
  }

  const int s_jl = threadIdx.x >> 2;  // 0..63
  const int s_g  = threadIdx.x & 3;   // 0..3 -> u32 pair rows 2g, 2g+1

  // ===================== Phase A: per-lane approx min over sample ============
  float lmind[Q];
  #pragma unroll
  for (int q = 0; q < Q; ++q) lmind[q] = INFINITY;

  for (int tile = 0; tile < TAU_TILES; ++tile) {
    const int j0 = tile * TJ;
    __syncthreads();
    #pragma unroll
    for (int p = 0; p < 4; ++p) {
      const int jl = s_jl + p * 64;
      const int j = j0 + jl;
      uint2 v = make_uint2(0u, 0u);
      if (j < N_PTS) v = ((const uint2*)(coords_h + j * 16))[s_g];
      cTh[(2 * s_g + 0) * HSTR + jl] = v.x;
      cTh[(2 * s_g + 1) * HSTR + jl] = v.y;
    }
    sqs[threadIdx.x] = (j0 + (int)threadIdx.x < N_PTS) ? sq[j0 + threadIdx.x] : 0.0f;
    __syncthreads();

    #pragma unroll
    for (int h = 0; h < 4; ++h) {
      const int jl = h * 64 + lane;
      const int j = j0 + jl;
      const float sqj = sqs[jl];
      unsigned cj[8];
      #pragma unroll
      for (int w = 0; w < 8; ++w) cj[w] = cTh[w * HSTR + jl];  // stride-1: conflict-free
      #pragma unroll
      for (int q = 0; q < Q; ++q) {
        float dot = 0.0f;
        #pragma unroll
        for (int w = 0; w < 8; ++w)
          dot = __builtin_amdgcn_fdot2(__builtin_bit_cast(h2, ciq[q][w]),
                                       __builtin_bit_cast(h2, cj[w]), dot, false);
        float d2a = fmaf(-2.0f, dot, sqi[q] + sqj);
        if (j == qbase + q) d2a = INFINITY;   // sample has no pad (1024 < N)
        lmind[q] = fminf(lmind[q], d2a);
      }
    }
  }

  // tau_q = 16th-smallest of the 64 lane minima (bitonic, take lane 15)
  float taug[Q];
  #pragma unroll
  for (int q = 0; q < Q; ++q) {
    float v = lmind[q];
    #pragma unroll
    for (int k = 2; k <= 64; k <<= 1) {
      #pragma unroll
      for (int s = k >> 1; s >= 1; s >>= 1) {
        const float o = __shfl_xor(v, s);
        const bool keepMin = (((lane & s) == 0) == ((lane & k) == 0));
        const float mn = fminf(v, o), mx = fmaxf(v, o);
        v = keepMin ? mn : mx;
      }
    }
    taug[q] = __shfl(v, 15) + MARGIN;   // sound gate threshold
  }

  // ===================== Phase B: gated scan, push survivor indices ==========
  for (int tile = 0; tile < NTILES; ++tile) {
    const int j0 = tile * TJ;
    __syncthreads();
    #pragma unroll
    for (int p = 0; p < 4; ++p) {
      const int jl = s_jl + p * 64;
      const int j = j0 + jl;
      uint2 v = make_uint2(0u, 0u);
      if (j < N_PTS) v = ((const uint2*)(coords_h + j * 16))[s_g];
      cTh[(2 * s_g + 0) * HSTR + jl] = v.x;
      cTh[(2 * s_g + 1) * HSTR + jl] = v.y;
    }
    sqs[threadIdx.x] = (j0 + (int)threadIdx.x < N_PTS) ? sq[j0 + threadIdx.x] : 0.0f;
    __syncthreads();

    #pragma unroll
    for (int h = 0; h < 4; ++h) {
      const int jl = h * 64 + lane;
      const int j = j0 + jl;
      const float sqj = sqs[jl];
      unsigned cj[8];
      #pragma unroll
      for (int w = 0; w < 8; ++w) cj[w] = cTh[w * HSTR + jl];
      #pragma unroll
      for (int q = 0; q < Q; ++q) {
        float dot = 0.0f;
        #pragma unroll
        for (int w = 0; w < 8; ++w)
          dot = __builtin_amdgcn_fdot2(__builtin_bit_cast(h2, ciq[q][w]),
                                       __builtin_bit_cast(h2, cj[w]), dot, false);
        const float d2a = fmaf(-2.0f, dot, sqi[q] + sqj);
        if (d2a <= taug[q]) {            // self/pad pass too; filtered in C
          const int wq = wave * Q + q;
          const int p = atomicAdd(&scnt[wq], 1);
          if (p < CAP) sbuf[wq][p] = (unsigned short)j;
        }
      }
    }
  }

  // ===================== Phase C: exact re-score + top-16 + fused out ========
  float aggv4[Q], fl4[Q];
  #pragma unroll
  for (int q = 0; q < Q; ++q) {
    const int wq = wave * Q + q;
    const int cq = scnt[wq];
    const int nread = (cq < CAP) ? cq : CAP;

    float ci[16];
    {
      const float4* cp = (const float4*)(coords + (qbase + q) * 16);
      *(float4*)&ci[0] = cp[0]; *(float4*)&ci[4] = cp[1];
      *(float4*)&ci[8] = cp[2]; *(float4*)&ci[12] = cp[3];
    }

    u64 k7[7];
    #pragma unroll
    for (int t = 0; t < 7; ++t) k7[t] = ((u64)(0x7F000000u + t) << 32);
    u64 kmax7 = ((u64)0x7F000006u << 32);

    #pragma unroll
    for (int t = 0; t < CAP / 64; ++t) {   // <=7 offers/lane: no eviction
      const int idx = t * 64 + lane;
      u64 key = ~0ull;
      if (idx < nread) {
        const int jj = sbuf[wq][idx];
        if (jj < N_PTS && jj != qbase + q) {
          const float4* cp = (const float4*)(coords + jj * 16);
          float cj[16];
          *(float4*)&cj[0]  = cp[0]; *(float4*)&cj[4]  = cp[1];
          *(float4*)&cj[8]  = cp[2]; *(float4*)&cj[12] = cp[3];
          float dot = 0.0f;
          #pragma unroll
          for (int d = 0; d < 16; ++d) dot = fmaf(ci[d], cj[d], dot);
          const float d2 = fmaxf(fmaf(-2.0f, dot, sqi[q] + sq[jj]), 0.0f);
          key = ((u64)__float_as_uint(d2) << 32) | (unsigned)jj;
        }
      }
      ins7(key, k7, kmax7);
    }

    u64 lmin = k7[0];
    #pragma unroll
    for (int t = 1; t < 7; ++t) lmin = (k7[t] < lmin) ? k7[t] : lmin;

    float aggv = 0.0f;
    for (int r = 0; r < KNN; ++r) {
      const u64 m = minbfly(lmin);
      if (lmin == m) {
        #pragma unroll
        for (int t = 0; t < 7; ++t) k7[t] = (k7[t] == m) ? ~0ull : k7[t];
        lmin = k7[0];
        #pragma unroll
        for (int t = 1; t < 7; ++t) lmin = (k7[t] < lmin) ? k7[t] : lmin;
      }
      const unsigned hi = (unsigned)(m >> 32);
      const bool ok = hi < 0x7F000000u;
      const float w = ok ? expf(-__uint_as_float(hi)) : 0.0f;
      const int jj = ok ? (int)(unsigned)(m & 0xFFFFFFFFull) : 0;
      aggv = fmaf(w, feats[jj * 64 + lane], aggv);
    }
    aggv4[q] = aggv;
    fl4[q] = feats[(qbase + q) * 64 + lane];
    if (lane == 0) flags[qbase + q] = (cq > CAP);
  }

  // fused output GEMM: shared Wo loads across the wave's 4 queries
  float acc[Q];
  #pragma unroll
  for (int q = 0; q < Q; ++q) acc[q] = bo[lane];
  #pragma unroll
  for (int f = 0; f < 64; ++f) {
    const float w1 = Wo[f * 64 + lane];
    const float w2 = Wo[(64 + f) * 64 + lane];
    #pragma unroll
    for (int q = 0; q < Q; ++q) {
      acc[q] = fmaf(__shfl(fl4[q], f), w1, acc[q]);
      acc[q] = fmaf(__shfl(aggv4[q], f), w2, acc[q]);
    }
  }
  #pragma unroll
  for (int q = 0; q < Q; ++q)
    out[(qbase + q) * 64 + lane] = acc[q];
}

// ---------------------------------------------------------------------------
// Kernel 2b: exact fallback for flagged (overflowed) queries — expected zero.
// Single-pass two half-table scan; slow exact path behind its own eviction
// flag. Recomputes the fused output row too.
// ---------------------------------------------------------------------------
__global__ __launch_bounds__(256) void knn_fixup_kernel(
    const float* __restrict__ coords, const float* __restrict__ sq,
    const float* __restrict__ feats, const int* __restrict__ flags,
    const float* __restrict__ Wo, const float* __restrict__ bo,
    float* __restrict__ out)
{
  const int wave = threadIdx.x >> 6;
  const int lane = threadIdx.x & 63;
  const int i = blockIdx.x * 4 + wave;
  if (i >= N_PTS) return;
  if (!flags[i]) return;
  float ci[16];
  #pragma unroll
  for (int d = 0; d < 16; ++d) ci[d] = coords[i * 16 + d];
  const float sqi = sq[i];

  u64 k8a[8], k8b[8], kmaxA, kmaxB;
  #pragma unroll
  for (int t = 0; t < 8; ++t) {
    k8a[t] = ((u64)(0x7F000000u + t) << 32);
    k8b[t] = ((u64)(0x7F000000u + t) << 32);
  }
  kmaxA = ((u64)0x7F000007u << 32);
  kmaxB = ((u64)0x7F000007u << 32);

  const int niter = (N_PTS + 63) / 64;  // 188
  for (int t = 0; t < niter; ++t) {
    const int j = t * 64 + lane;
    float4 c0 = make_float4(0,0,0,0), c1 = c0, c2 = c0, c3 = c0;
    float sqj = 0.0f;
    if (j < N_PTS) {
      const float4* cp = (const float4*)(coords + j * 16);
      c0 = cp[0]; c1 = cp[1]; c2 = cp[2]; c3 = cp[3];
      sqj = sq[j];
    }
    float dot = ci[0]*c0.x + ci[1]*c0.y + ci[2]*c0.z + ci[3]*c0.w
              + ci[4]*c1.x + ci[5]*c1.y + ci[6]*c1.z + ci[7]*c1.w
              + ci[8]*c2.x + ci[9]*c2.y + ci[10]*c2.z + ci[11]*c2.w
              + ci[12]*c3.x + ci[13]*c3.y + ci[14]*c3.z + ci[15]*c3.w;
    float d2 = fmaxf(fmaf(-2.0f, dot, sqi + sqj), 0.0f);
    const unsigned hi = (j == i || j >= N_PTS) ? 0xFFFFFFFFu : __float_as_uint(d2);
    const u64 key = ((u64)hi << 32) | (unsigned)j;
    if (t & 1) ins8(key, k8a, kmaxA);
    else       ins8(key, k8b, kmaxB);
  }

  u64 tab[16];
  #pragma unroll
  for (int t = 0; t < 8; ++t) { tab[t] = k8a[t]; tab[8 + t] = k8b[t]; }
  u64 lmin = tab[0];
  #pragma unroll
  for (int t = 1; t < 16; ++t) lmin = (tab[t] < lmin) ? tab[t] : lmin;

  float aggv = 0.0f;
  u64 T16 = 0;
  for (int r = 0; r < KNN; ++r) {
    const u64 m = minbfly(lmin);
    if (lmin == m) {
      #pragma unroll
      for (int t = 0; t < 16; ++t) tab[t] = (tab[t] == m) ? ~0ull : tab[t];
      lmin = tab[0];
      #pragma unroll
      for (int t = 1; t < 16; ++t) lmin = (tab[t] < lmin) ? tab[t] : lmin;
    }
    const unsigned hi = (unsigned)(m >> 32);
    const bool ok = hi < 0x7F000000u;
    const float w = ok ? expf(-__uint_as_float(hi)) : 0.0f;
    const int jj = ok ? (int)(unsigned)(m & 0xFFFFFFFFull) : 0;
    aggv = fmaf(w, feats[jj * 64 + lane], aggv);
    T16 = m;
  }

  if (__any((kmaxA < T16) || (kmaxB < T16))) {
    aggv = 0.0f;
    u64 prev = 0;
    for (int r = 0; r < KNN; ++r) {
      u64 best = ~0ull;
      for (int j = lane; j < N_PTS; j += 64) {
        float dot = 0.0f;
        #pragma unroll
        for (int d = 0; d < 16; ++d) dot = fmaf(ci[d], coords[j * 16 + d], dot);
        const float d2 = fmaxf(fmaf(-2.0f, dot, sqi + sq[j]), 0.0f);
        const unsigned hi = (j == i) ? 0xFFFFFFFFu : __float_as_uint(d2);
        const u64 key = ((u64)hi << 32) | (unsigned)j;
        const bool cand = (r == 0) || (key > prev);
        if (cand && key < best) best = key;
      }
      const u64 m = minbfly(best);
      prev = m;
      const unsigned hi = (unsigned)(m >> 32);
      const bool ok = hi < 0x7F000000u;
      const float w = ok ? expf(-__uint_as_float(hi)) : 0.0f;
      const int jj = ok ? (int)(unsigned)(m & 0xFFFFFFFFull) : 0;
      aggv = fmaf(w, feats[jj * 64 + lane], aggv);
    }
  }

  // fused output row
  const float fl = feats[i * 64 + lane];
  float acc = bo[lane];
  #pragma unroll
  for (int f = 0; f < 64; ++f) {
    acc = fmaf(__shfl(fl, f),   Wo[f * 64 + lane],        acc);
    acc = fmaf(__shfl(aggv, f), Wo[(64 + f) * 64 + lane], acc);
  }
  out[i * 64 + lane] = acc;
}

extern "C" void kernel_launch(void* const* d_in, const int* in_sizes, int n_in,
                              void* d_out, int out_size, void* d_ws, size_t ws_size,
                              hipStream_t stream) {
  const float* x  = (const float*)d_in[0];
  const float* Wf = (const float*)d_in[1];
  const float* bf = (const float*)d_in[2];
  const float* Wl = (const float*)d_in[3];
  const float* bl = (const float*)d_in[4];
  const float* Wo = (const float*)d_in[5];
  const float* bo = (const float*)d_in[6];
  float* out = (float*)d_out;

  char* ws = (char*)d_ws;
  float*     feats    = (float*)(ws);                 // 3,072,000 B
  float*     coords   = (float*)(ws + 3072000);       //   768,000 B
  float*     sqv      = (float*)(ws + 3840000);       //    48,000 B
  _Float16*  coords_h = (_Float16*)(ws + 3888000);    //   384,000 B
  int*       flags    = (int*)(ws + 4272000);         //    48,000 B

  encoder_kernel<<<3000, 256, 0, stream>>>(x, Wf, bf, Wl, bl, feats, coords, coords_h, sqv);
  knn_agg_kernel<<<N_PTS / (WPB * Q), 256, 0, stream>>>(coords, coords_h, sqv, feats, Wo, bo, out, flags);
  knn_fixup_kernel<<<3000, 256, 0, stream>>>(coords, sqv, feats, flags, Wo, bo, out);
}

// Round 10
// 301.542 us; speedup vs baseline: 1.8004x; 1.8004x over previous
//
#include <hip/hip_runtime.h>
#include <math.h>

typedef unsigned long long u64;
typedef _Float16 h2 __attribute__((ext_vector_type(2)));

#define N_PTS 12000
#define KNN 16
#define TJ 256     // candidate tile size
#define Q 4        // queries per wave
#define WPB 2      // waves per block (128-thread blocks)
#define NTILES ((N_PTS + TJ - 1) / TJ)   // 47
#define TAU_TILES 8                      // sample = first 2048 points
#define CAP 384                          // survivor capacity; 6 offers/lane
#define HROW 12                          // u32 row stride per point (48 B, 16B-aligned)
#define MARGIN 0.08f                     // > 2*m, m = f16 d2 error bound ~0.032

// ---------------------------------------------------------------------------
// Kernel 1: encoders. feats = tanh(x@Wf+bf); coords = tanh(x@Wl+bl) fp32+f16;
// sq = |coords|^2. One wave per row.
// ---------------------------------------------------------------------------
__global__ __launch_bounds__(256) void encoder_kernel(
    const float* __restrict__ x, const float* __restrict__ Wf, const float* __restrict__ bf,
    const float* __restrict__ Wl, const float* __restrict__ bl,
    float* __restrict__ feats, float* __restrict__ coords, _Float16* __restrict__ coords_h,
    float* __restrict__ sq)
{
  const int wave = threadIdx.x >> 6;
  const int lane = threadIdx.x & 63;
  const int i = blockIdx.x * 4 + wave;
  if (i >= N_PTS) return;
  float xv = x[i * 64 + lane];
  float accf = bf[lane];
  float accc = bl[lane & 15];
  #pragma unroll
  for (int k = 0; k < 64; ++k) {
    float xk = __shfl(xv, k);
    accf = fmaf(xk, Wf[k * 64 + lane], accf);
    accc = fmaf(xk, Wl[k * 16 + (lane & 15)], accc);
  }
  feats[i * 64 + lane] = tanhf(accf);
  float c = tanhf(accc);
  float cc = (lane < 16) ? c * c : 0.0f;
  cc += __shfl_xor(cc, 1);
  cc += __shfl_xor(cc, 2);
  cc += __shfl_xor(cc, 4);
  cc += __shfl_xor(cc, 8);
  if (lane < 16) {
    coords[i * 16 + lane] = c;
    coords_h[i * 16 + lane] = (_Float16)c;
  }
  if (lane == 0) sq[i] = cc;
}

// ---------------------------------------------------------------------------
// u64-key helpers. Keys (f32bits(d2)<<32)|j unique; sentinels (0x7F00000t<<32)
// exceed any real key; ~0ull matches no slot.
// ---------------------------------------------------------------------------
__device__ __forceinline__ void ins6(u64 key, u64* k6, u64& kmax) {
  const u64 om = (key < kmax) ? kmax : ~0ull;
  #pragma unroll
  for (int t = 0; t < 6; ++t)
    k6[t] = (k6[t] == om) ? key : k6[t];
  u64 a = k6[0] > k6[1] ? k6[0] : k6[1];
  u64 b = k6[2] > k6[3] ? k6[2] : k6[3];
  u64 c = k6[4] > k6[5] ? k6[4] : k6[5];
  a = a > b ? a : b;
  kmax = a > c ? a : c;
}

__device__ __forceinline__ void ins8(u64 key, u64* k8, u64& kmax) {
  const u64 om = (key < kmax) ? kmax : ~0ull;
  #pragma unroll
  for (int t = 0; t < 8; ++t)
    k8[t] = (k8[t] == om) ? key : k8[t];
  u64 a = k8[0] > k8[1] ? k8[0] : k8[1];
  u64 b = k8[2] > k8[3] ? k8[2] : k8[3];
  u64 c = k8[4] > k8[5] ? k8[4] : k8[5];
  u64 d = k8[6] > k8[7] ? k8[6] : k8[7];
  a = a > b ? a : b;
  c = c > d ? c : d;
  kmax = a > c ? a : c;
}

__device__ __forceinline__ u64 shflx_u64(u64 v, int off) {
  int lo = __shfl_xor((int)(unsigned)v, off);
  int hi = __shfl_xor((int)(unsigned)(v >> 32), off);
  return ((u64)(unsigned)hi << 32) | (unsigned)lo;
}

__device__ __forceinline__ u64 minbfly(u64 m) {
  #pragma unroll
  for (int off = 32; off >= 1; off >>= 1) {
    u64 o = shflx_u64(m, off);
    m = (o < m) ? o : m;
  }
  return m;
}

// ---------------------------------------------------------------------------
// Kernel 2: KNN + gaussian aggregation. Wave = 4 queries, block = 2 waves.
// Phase A (f16 fdot2): per-lane min over 2048-pt sample (self excluded);
//   tau = 16th order stat of lane minima + MARGIN (sound: exact-16th <=
//   tau_a + m, so every true member's approx d2 <= tau_a + 2m < gate).
// Phase B (f16 fdot2): full scan; approx d2 <= gate pushes u16 index
//   (self/pad pass, filtered in C). Overflow -> flag -> fixup.
// Phase C: exact fp32 re-score (reference-identical fmaf chain), exact
//   top-16 via 6-slot tables (<=6 offers/lane: no eviction) + minbfly.
// ---------------------------------------------------------------------------
__global__ __launch_bounds__(128) void knn_agg_kernel(
    const float* __restrict__ coords, const _Float16* __restrict__ coords_h,
    const float* __restrict__ sq, const float* __restrict__ feats,
    float* __restrict__ agg, int* __restrict__ flags)
{
  __shared__ unsigned cTh[TJ * HROW];             // 12288 B
  __shared__ float sqs[TJ];                       //  1024 B
  __shared__ unsigned short sbuf[WPB * Q][CAP];   //  6144 B
  __shared__ int scnt[WPB * Q];                   //    32 B

  const int tid = threadIdx.x;       // 0..127
  const int lane = tid & 63;
  const int wave = tid >> 6;
  const int qbase = blockIdx.x * (WPB * Q) + wave * Q;

  if (tid < WPB * Q) scnt[tid] = 0;

  unsigned ciq[Q][8];
  float sqi[Q];
  #pragma unroll
  for (int q = 0; q < Q; ++q) {
    const uint4* cp = (const uint4*)(coords_h + (qbase + q) * 16);
    uint4 a = cp[0], b = cp[1];
    ciq[q][0] = a.x; ciq[q][1] = a.y; ciq[q][2] = a.z; ciq[q][3] = a.w;
    ciq[q][4] = b.x; ciq[q][5] = b.y; ciq[q][6] = b.z; ciq[q][7] = b.w;
    sqi[q] = sq[qbase + q];
  }

  // ===================== Phase A: per-lane approx min over sample ============
  float lmind[Q];
  #pragma unroll
  for (int q = 0; q < Q; ++q) lmind[q] = INFINITY;

  for (int tile = 0; tile < TAU_TILES; ++tile) {
    const int j0 = tile * TJ;
    __syncthreads();
    #pragma unroll
    for (int p = 0; p < 2; ++p) {
      const int jl = tid + p * 128;
      const int j = j0 + jl;   // sample tiles: always < N_PTS
      const uint4* cp = (const uint4*)(coords_h + j * 16);
      *(uint4*)&cTh[jl * HROW + 0] = cp[0];
      *(uint4*)&cTh[jl * HROW + 4] = cp[1];
      sqs[jl] = sq[j];
    }
    __syncthreads();

    #pragma unroll
    for (int h = 0; h < 4; ++h) {
      const int jl = h * 64 + lane;
      const int j = j0 + jl;
      const float sqj = sqs[jl];
      const uint4 u0 = *(const uint4*)&cTh[jl * HROW + 0];
      const uint4 u1 = *(const uint4*)&cTh[jl * HROW + 4];
      unsigned cj[8] = {u0.x, u0.y, u0.z, u0.w, u1.x, u1.y, u1.z, u1.w};
      #pragma unroll
      for (int q = 0; q < Q; ++q) {
        float dot = 0.0f;
        #pragma unroll
        for (int w = 0; w < 8; ++w)
          dot = __builtin_amdgcn_fdot2(__builtin_bit_cast(h2, ciq[q][w]),
                                       __builtin_bit_cast(h2, cj[w]), dot, false);
        float d2a = fmaf(-2.0f, dot, sqi[q] + sqj);
        if (j == qbase + q) d2a = INFINITY;
        lmind[q] = fminf(lmind[q], d2a);
      }
    }
  }

  float taug[Q];
  #pragma unroll
  for (int q = 0; q < Q; ++q) {
    float v = lmind[q];
    #pragma unroll
    for (int k = 2; k <= 64; k <<= 1) {
      #pragma unroll
      for (int s = k >> 1; s >= 1; s >>= 1) {
        const float o = __shfl_xor(v, s);
        const bool keepMin = (((lane & s) == 0) == ((lane & k) == 0));
        const float mn = fminf(v, o), mx = fmaxf(v, o);
        v = keepMin ? mn : mx;
      }
    }
    taug[q] = __shfl(v, 15) + MARGIN;   // sound gate
  }

  // ===================== Phase B: gated scan, push survivor indices ==========
  for (int tile = 0; tile < NTILES; ++tile) {
    const int j0 = tile * TJ;
    __syncthreads();
    #pragma unroll
    for (int p = 0; p < 2; ++p) {
      const int jl = tid + p * 128;
      const int j = j0 + jl;
      uint4 a = make_uint4(0u,0u,0u,0u), b = a;
      float sv = 0.0f;
      if (j < N_PTS) {
        const uint4* cp = (const uint4*)(coords_h + j * 16);
        a = cp[0]; b = cp[1]; sv = sq[j];
      }
      *(uint4*)&cTh[jl * HROW + 0] = a;
      *(uint4*)&cTh[jl * HROW + 4] = b;
      sqs[jl] = sv;
    }
    __syncthreads();

    #pragma unroll
    for (int h = 0; h < 4; ++h) {
      const int jl = h * 64 + lane;
      const int j = j0 + jl;
      const float sqj = sqs[jl];
      const uint4 u0 = *(const uint4*)&cTh[jl * HROW + 0];
      const uint4 u1 = *(const uint4*)&cTh[jl * HROW + 4];
      unsigned cj[8] = {u0.x, u0.y, u0.z, u0.w, u1.x, u1.y, u1.z, u1.w};
      #pragma unroll
      for (int q = 0; q < Q; ++q) {
        float dot = 0.0f;
        #pragma unroll
        for (int w = 0; w < 8; ++w)
          dot = __builtin_amdgcn_fdot2(__builtin_bit_cast(h2, ciq[q][w]),
                                       __builtin_bit_cast(h2, cj[w]), dot, false);
        const float d2a = fmaf(-2.0f, dot, sqi[q] + sqj);
        if (d2a <= taug[q]) {            // self/pad pass; filtered in Phase C
          const int wq = wave * Q + q;
          const int p = atomicAdd(&scnt[wq], 1);
          if (p < CAP) sbuf[wq][p] = (unsigned short)j;
        }
      }
    }
  }

  // ===================== Phase C: exact fp32 re-score + top-16 ===============
  #pragma unroll
  for (int q = 0; q < Q; ++q) {
    const int wq = wave * Q + q;
    const int cq = scnt[wq];
    const int nread = (cq < CAP) ? cq : CAP;

    float ci[16];
    {
      const float4* cp = (const float4*)(coords + (qbase + q) * 16);
      *(float4*)&ci[0] = cp[0]; *(float4*)&ci[4] = cp[1];
      *(float4*)&ci[8] = cp[2]; *(float4*)&ci[12] = cp[3];
    }

    u64 k6[6];
    #pragma unroll
    for (int t = 0; t < 6; ++t) k6[t] = ((u64)(0x7F000000u + t) << 32);
    u64 kmax6 = ((u64)0x7F000005u << 32);

    #pragma unroll
    for (int t = 0; t < CAP / 64; ++t) { // <=6 offers/lane: no eviction
      const int idx = t * 64 + lane;
      u64 key = ~0ull;
      if (idx < nread) {
        const int jj = sbuf[wq][idx];
        if (jj < N_PTS && jj != qbase + q) {
          const float4* cp = (const float4*)(coords + jj * 16);
          float cj[16];
          *(float4*)&cj[0]  = cp[0]; *(float4*)&cj[4]  = cp[1];
          *(float4*)&cj[8]  = cp[2]; *(float4*)&cj[12] = cp[3];
          float dot = 0.0f;
          #pragma unroll
          for (int d = 0; d < 16; ++d) dot = fmaf(ci[d], cj[d], dot);
          const float d2 = fmaxf(fmaf(-2.0f, dot, sqi[q] + sq[jj]), 0.0f);
          key = ((u64)__float_as_uint(d2) << 32) | (unsigned)jj;
        }
      }
      ins6(key, k6, kmax6);
    }

    u64 lmin = k6[0];
    #pragma unroll
    for (int t = 1; t < 6; ++t) lmin = (k6[t] < lmin) ? k6[t] : lmin;

    float aggv = 0.0f;
    for (int r = 0; r < KNN; ++r) {
      const u64 m = minbfly(lmin);
      if (lmin == m) {
        #pragma unroll
        for (int t = 0; t < 6; ++t) k6[t] = (k6[t] == m) ? ~0ull : k6[t];
        lmin = k6[0];
        #pragma unroll
        for (int t = 1; t < 6; ++t) lmin = (k6[t] < lmin) ? k6[t] : lmin;
      }
      const unsigned hi = (unsigned)(m >> 32);
      const bool ok = hi < 0x7F000000u;
      const float w = ok ? expf(-__uint_as_float(hi)) : 0.0f;
      const int jj = ok ? (int)(unsigned)(m & 0xFFFFFFFFull) : 0;
      aggv = fmaf(w, feats[jj * 64 + lane], aggv);
    }
    agg[(qbase + q) * 64 + lane] = aggv;
    if (lane == 0) flags[qbase + q] = (cq > CAP);
  }
}

// ---------------------------------------------------------------------------
// Kernel 2b: exact fallback for flagged (overflowed) queries — expected zero.
// ---------------------------------------------------------------------------
__global__ __launch_bounds__(256) void knn_fixup_kernel(
    const float* __restrict__ coords, const float* __restrict__ sq,
    const float* __restrict__ feats, const int* __restrict__ flags,
    float* __restrict__ agg)
{
  const int wave = threadIdx.x >> 6;
  const int lane = threadIdx.x & 63;
  const int i = blockIdx.x * 4 + wave;
  if (i >= N_PTS) return;
  if (!flags[i]) return;
  float ci[16];
  #pragma unroll
  for (int d = 0; d < 16; ++d) ci[d] = coords[i * 16 + d];
  const float sqi = sq[i];

  u64 k8a[8], k8b[8], kmaxA, kmaxB;
  #pragma unroll
  for (int t = 0; t < 8; ++t) {
    k8a[t] = ((u64)(0x7F000000u + t) << 32);
    k8b[t] = ((u64)(0x7F000000u + t) << 32);
  }
  kmaxA = ((u64)0x7F000007u << 32);
  kmaxB = ((u64)0x7F000007u << 32);

  const int niter = (N_PTS + 63) / 64;  // 188
  for (int t = 0; t < niter; ++t) {
    const int j = t * 64 + lane;
    float4 c0 = make_float4(0,0,0,0), c1 = c0, c2 = c0, c3 = c0;
    float sqj = 0.0f;
    if (j < N_PTS) {
      const float4* cp = (const float4*)(coords + j * 16);
      c0 = cp[0]; c1 = cp[1]; c2 = cp[2]; c3 = cp[3];
      sqj = sq[j];
    }
    float dot = ci[0]*c0.x + ci[1]*c0.y + ci[2]*c0.z + ci[3]*c0.w
              + ci[4]*c1.x + ci[5]*c1.y + ci[6]*c1.z + ci[7]*c1.w
              + ci[8]*c2.x + ci[9]*c2.y + ci[10]*c2.z + ci[11]*c2.w
              + ci[12]*c3.x + ci[13]*c3.y + ci[14]*c3.z + ci[15]*c3.w;
    float d2 = fmaxf(fmaf(-2.0f, dot, sqi + sqj), 0.0f);
    const unsigned hi = (j == i || j >= N_PTS) ? 0xFFFFFFFFu : __float_as_uint(d2);
    const u64 key = ((u64)hi << 32) | (unsigned)j;
    if (t & 1) ins8(key, k8a, kmaxA);
    else       ins8(key, k8b, kmaxB);
  }

  u64 tab[16];
  #pragma unroll
  for (int t = 0; t < 8; ++t) { tab[t] = k8a[t]; tab[8 + t] = k8b[t]; }
  u64 lmin = tab[0];
  #pragma unroll
  for (int t = 1; t < 16; ++t) lmin = (tab[t] < lmin) ? tab[t] : lmin;

  float aggv = 0.0f;
  u64 T16 = 0;
  for (int r = 0; r < KNN; ++r) {
    const u64 m = minbfly(lmin);
    if (lmin == m) {
      #pragma unroll
      for (int t = 0; t < 16; ++t) tab[t] = (tab[t] == m) ? ~0ull : tab[t];
      lmin = tab[0];
      #pragma unroll
      for (int t = 1; t < 16; ++t) lmin = (tab[t] < lmin) ? tab[t] : lmin;
    }
    const unsigned hi = (unsigned)(m >> 32);
    const bool ok = hi < 0x7F000000u;
    const float w = ok ? expf(-__uint_as_float(hi)) : 0.0f;
    const int jj = ok ? (int)(unsigned)(m & 0xFFFFFFFFull) : 0;
    aggv = fmaf(w, feats[jj * 64 + lane], aggv);
    T16 = m;
  }

  if (__any((kmaxA < T16) || (kmaxB < T16))) {
    aggv = 0.0f;
    u64 prev = 0;
    for (int r = 0; r < KNN; ++r) {
      u64 best = ~0ull;
      for (int j = lane; j < N_PTS; j += 64) {
        float dot = 0.0f;
        #pragma unroll
        for (int d = 0; d < 16; ++d) dot = fmaf(ci[d], coords[j * 16 + d], dot);
        const float d2 = fmaxf(fmaf(-2.0f, dot, sqi + sq[j]), 0.0f);
        const unsigned hi = (j == i) ? 0xFFFFFFFFu : __float_as_uint(d2);
        const u64 key = ((u64)hi << 32) | (unsigned)j;
        const bool cand = (r == 0) || (key > prev);
        if (cand && key < best) best = key;
      }
      const u64 m = minbfly(best);
      prev = m;
      const unsigned hi = (unsigned)(m >> 32);
      const bool ok = hi < 0x7F000000u;
      const float w = ok ? expf(-__uint_as_float(hi)) : 0.0f;
      const int jj = ok ? (int)(unsigned)(m & 0xFFFFFFFFull) : 0;
      aggv = fmaf(w, feats[jj * 64 + lane], aggv);
    }
  }
  agg[i * 64 + lane] = aggv;
}

// ---------------------------------------------------------------------------
// Kernel 3: out = concat(feats, agg) @ W_out + b_out. Two rows per thread
// share the Wo loads.
// ---------------------------------------------------------------------------
__global__ __launch_bounds__(256) void out_kernel(
    const float* __restrict__ feats, const float* __restrict__ agg,
    const float* __restrict__ Wo, const float* __restrict__ bo,
    float* __restrict__ out)
{
  const int idx = blockIdx.x * 256 + threadIdx.x;
  const int pr = idx >> 6, o = idx & 63;
  const int i0 = pr * 2;
  if (i0 >= N_PTS) return;
  float acc0 = bo[o], acc1 = acc0;
  #pragma unroll
  for (int f = 0; f < 64; ++f) {
    const float w1 = Wo[f * 64 + o];
    acc0 = fmaf(feats[i0 * 64 + f], w1, acc0);
    acc1 = fmaf(feats[(i0 + 1) * 64 + f], w1, acc1);
  }
  #pragma unroll
  for (int f = 0; f < 64; ++f) {
    const float w2 = Wo[(64 + f) * 64 + o];
    acc0 = fmaf(agg[i0 * 64 + f], w2, acc0);
    acc1 = fmaf(agg[(i0 + 1) * 64 + f], w2, acc1);
  }
  out[i0 * 64 + o] = acc0;
  out[(i0 + 1) * 64 + o] = acc1;
}

extern "C" void kernel_launch(void* const* d_in, const int* in_sizes, int n_in,
                              void* d_out, int out_size, void* d_ws, size_t ws_size,
                              hipStream_t stream) {
  const float* x  = (const float*)d_in[0];
  const float* Wf = (const float*)d_in[1];
  const float* bf = (const float*)d_in[2];
  const float* Wl = (const float*)d_in[3];
  const float* bl = (const float*)d_in[4];
  const float* Wo = (const float*)d_in[5];
  const float* bo = (const float*)d_in[6];
  float* out = (float*)d_out;

  char* ws = (char*)d_ws;
  float*     feats    = (float*)(ws);                 // 3,072,000 B
  float*     coords   = (float*)(ws + 3072000);       //   768,000 B
  float*     sqv      = (float*)(ws + 3840000);       //    48,000 B
  _Float16*  coords_h = (_Float16*)(ws + 3888000);    //   384,000 B
  float*     agg      = (float*)(ws + 4272000);       // 3,072,000 B
  int*       flags    = (int*)(ws + 7344000);         //    48,000 B

  encoder_kernel<<<3000, 256, 0, stream>>>(x, Wf, bf, Wl, bl, feats, coords, coords_h, sqv);
  knn_agg_kernel<<<N_PTS / (WPB * Q), 128, 0, stream>>>(coords, coords_h, sqv, feats, agg, flags);
  knn_fixup_kernel<<<3000, 256, 0, stream>>>(coords, sqv, feats, flags, agg);
  out_kernel<<<1500, 256, 0, stream>>>(feats, agg, Wo, bo, out);
}